// Round 1
// 692.564 us; speedup vs baseline: 1.0220x; 1.0220x over previous
//
#include <hip/hip_runtime.h>

// B=16, C=2048, HID=256, HW=1024. fp32 I/O.
// Pipeline: prep (X->f16 transpose + V16 + W16) ; proj (f16 GEMM) ; scores (f16 GEMM) ;
// softmax (f32 in, f16 A out in-place) ; av (f16 GEMM) ; copy qf -> out[:,0:2048] LAST.
// All GEMMs: 128x128 tile, BK=64, global_load_lds dwordx4 staging, XOR-swizzled slots (m97 structure).
#define NB   16
#define NC   2048
#define NHID 256
#define NHW  1024

using half4_t  = __attribute__((ext_vector_type(4))) _Float16;
using half8_t  = __attribute__((ext_vector_type(8))) _Float16;
using float4_t = __attribute__((ext_vector_type(4))) float;

#define OUT_BATCH_BYTES ((size_t)(4096u * 1024u) * 4u)   /* 16 MiB per batch in out */

// ---------------- async 16B global -> LDS ----------------
__device__ __forceinline__ void async_load16(const void* g, void* l) {
    __builtin_amdgcn_global_load_lds((__attribute__((address_space(1))) void*)g,
                                     (__attribute__((address_space(3))) void*)l, 16, 0, 0);
}

// Stage one 128x64(half) tile: LDS linear (wave-uniform base + lane*16), global source
// pre-swizzled so that LDS 16B-slot sw of row holds logical slot sw^(row&7).
__device__ __forceinline__ void stage_async(const _Float16* __restrict__ src, size_t stride_h,
                                            _Float16* __restrict__ lds, int t) {
    #pragma unroll
    for (int i = 0; i < 4; ++i) {
        const int o   = i * 4096 + t * 16;          // byte offset in 16 KiB tile
        const int row = o >> 7;                     // 128 B per row
        const int s   = ((o >> 4) & 7) ^ (row & 7); // logical slot for this LDS slot
        const _Float16* g = src + (size_t)row * stride_h + s * 8;
        async_load16(g, (char*)lds + o);
    }
}

// Fragment read with the same involution: logical slot (kk*4+quad) lives at slot^(row&7).
__device__ __forceinline__ half8_t frag_read(const _Float16* __restrict__ lds, int row, int kk, int quad) {
    const int s = (kk * 4 + quad) ^ (row & 7);
    return *(const half8_t*)((const char*)lds + row * 128 + s * 16);
}

#define ACC_INIT(acc) \
    _Pragma("unroll") for (int i_ = 0; i_ < 4; ++i_) \
    _Pragma("unroll") for (int j_ = 0; j_ < 4; ++j_) \
    _Pragma("unroll") for (int r_ = 0; r_ < 4; ++r_) acc[i_][j_][r_] = 0.f;

// D[128][128] += A[128][K] * B[128][K]^T over K, 4 waves each 64x64.
__device__ __forceinline__ void gemm_f16(const _Float16* __restrict__ A, size_t lda,
                                         const _Float16* __restrict__ B, size_t ldb,
                                         int K, _Float16* __restrict__ As, _Float16* __restrict__ Bs,
                                         float4_t acc[4][4]) {
    const int t = threadIdx.x;
    const int l = t & 63, quad = l >> 4, l15 = l & 15;
    const int w = t >> 6;
    const int wr = (w >> 1) * 64, wc = (w & 1) * 64;
    for (int k0 = 0; k0 < K; k0 += 64) {
        stage_async(A + k0, lda, As, t);
        stage_async(B + k0, ldb, Bs, t);
        __syncthreads();   // compiler drains vmcnt before barrier -> tiles visible
        #pragma unroll
        for (int kk = 0; kk < 2; ++kk) {
            half8_t af[4], bf[4];
            #pragma unroll
            for (int i = 0; i < 4; ++i) af[i] = frag_read(As, wr + i * 16 + l15, kk, quad);
            #pragma unroll
            for (int j = 0; j < 4; ++j) bf[j] = frag_read(Bs, wc + j * 16 + l15, kk, quad);
            #pragma unroll
            for (int i = 0; i < 4; ++i)
                #pragma unroll
                for (int j = 0; j < 4; ++j)
                    acc[i][j] = __builtin_amdgcn_mfma_f32_16x16x32_f16(af[i], bf[j], acc[i][j], 0, 0, 0);
        }
        __syncthreads();
    }
}

// ---------------- prep: X[c][hw] f32 -> X16T[hw][c] f16 (+ V16 for pf) ----------------
// grid (16 hw-tiles, 32 c-tiles, 32 = which*16+b), 256 threads, 64x64 tiles
__global__ __launch_bounds__(256) void prep_kernel(
    const float* __restrict__ qf, const float* __restrict__ pf,
    _Float16* __restrict__ qT, float* __restrict__ out) {
    __shared__ _Float16 tile[64][72];
    const int z = blockIdx.z, which = z >> 4, b = z & 15;
    const int c0 = blockIdx.y * 64, h0 = blockIdx.x * 64;
    const float* X = (which ? pf : qf) + (size_t)b * NC * NHW;
    _Float16* T = which ? (_Float16*)((char*)out + (size_t)b * OUT_BATCH_BYTES + (4u << 20))
                        : (qT + (size_t)b * NHW * NC);
    const int t = threadIdx.x;
    const int row = t >> 2, seg = t & 3;
    const float* src = X + (size_t)(c0 + row) * NHW + h0 + seg * 16;
    float4 v[4];
    #pragma unroll
    for (int i = 0; i < 4; ++i) v[i] = *(const float4*)(src + i * 4);
    half8_t h[2];
    #pragma unroll
    for (int i = 0; i < 2; ++i) {
        #pragma unroll
        for (int e = 0; e < 4; ++e) {
            h[i][e]     = (_Float16)((&v[2 * i].x)[e]);
            h[i][4 + e] = (_Float16)((&v[2 * i + 1].x)[e]);
        }
        *(half8_t*)&tile[row][seg * 16 + i * 8] = h[i];
    }
    if (which) {  // V16[c][hw] natural layout, per-batch lo scratch in out
        _Float16* vd = (_Float16*)((char*)out + (size_t)b * OUT_BATCH_BYTES)
                       + (size_t)(c0 + row) * NHW + h0 + seg * 16;
        *(half8_t*)vd = h[0];
        *(half8_t*)(vd + 8) = h[1];
    }
    __syncthreads();
    const int hr = t >> 2;  // hw row within tile
    half8_t o[2];
    #pragma unroll
    for (int i = 0; i < 2; ++i)
        #pragma unroll
        for (int e = 0; e < 8; ++e) o[i][e] = tile[seg * 16 + i * 8 + e][hr];
    _Float16* od = T + (size_t)(h0 + hr) * NC + c0 + seg * 16;
    *(half8_t*)od = o[0];
    *(half8_t*)(od + 8) = o[1];
}

// ---------------- W f32[256][2048] -> f16 ----------------
__global__ __launch_bounds__(256) void wcvt_kernel(const float* __restrict__ W, _Float16* __restrict__ W16) {
    const int idx = (blockIdx.x * 256 + threadIdx.x) * 8;
    float4 a = *(const float4*)(W + idx);
    float4 c = *(const float4*)(W + idx + 4);
    half8_t h;
    h[0] = (_Float16)a.x; h[1] = (_Float16)a.y; h[2] = (_Float16)a.z; h[3] = (_Float16)a.w;
    h[4] = (_Float16)c.x; h[5] = (_Float16)c.y; h[6] = (_Float16)c.z; h[7] = (_Float16)c.w;
    *(half8_t*)(W16 + idx) = h;
}

// ---------------- proj: Q^T/K^T[hw][hid] = X16T * W16^T + b ; K=2048 ----------------
// grid (2, 8, 32): z>=16 -> K from pf16T
__global__ __launch_bounds__(256) void proj16_kernel(
    const _Float16* __restrict__ qT, const float* __restrict__ out_scratch,
    const _Float16* __restrict__ W16, const float* __restrict__ bias,
    _Float16* __restrict__ Q16, _Float16* __restrict__ K16) {
    __shared__ __attribute__((aligned(16))) _Float16 As[8192];
    __shared__ __attribute__((aligned(16))) _Float16 Bs[8192];
    const int z = blockIdx.z, which = z >> 4, b = z & 15;
    const _Float16* X = which
        ? (const _Float16*)((const char*)out_scratch + (size_t)b * OUT_BATCH_BYTES + (4u << 20))
        : (qT + (size_t)b * NHW * NC);
    _Float16* O = (which ? K16 : Q16) + (size_t)b * NHW * NHID;
    const int m0 = blockIdx.y * 128, n0 = blockIdx.x * 128;
    float4_t acc[4][4];
    ACC_INIT(acc)
    gemm_f16(X + (size_t)m0 * NC, NC, W16 + (size_t)n0 * NC, NC, NC, As, Bs, acc);
    const int t = threadIdx.x, l = t & 63, quad = l >> 4, l15 = l & 15, w = t >> 6;
    const int wr = (w >> 1) * 64, wc = (w & 1) * 64;
    #pragma unroll
    for (int j = 0; j < 4; ++j) {
        const float bv = bias[n0 + wc + j * 16 + l15];
        #pragma unroll
        for (int i = 0; i < 4; ++i)
            #pragma unroll
            for (int r = 0; r < 4; ++r) {
                int hw  = m0 + wr + i * 16 + quad * 4 + r;
                int hid = n0 + wc + j * 16 + l15;
                O[(size_t)hw * NHID + hid] = (_Float16)(acc[i][j][r] + bv);
            }
    }
}

// ---------------- scores: S[q1][q2] = Q^T . K^T ; K=256 ----------------
// grid (8, 8, 16)
__global__ __launch_bounds__(256) void scores16_kernel(
    const _Float16* __restrict__ Q16, const _Float16* __restrict__ K16, float* __restrict__ S) {
    __shared__ __attribute__((aligned(16))) _Float16 As[8192];
    __shared__ __attribute__((aligned(16))) _Float16 Bs[8192];
    const int b = blockIdx.z;
    const int m0 = blockIdx.y * 128, n0 = blockIdx.x * 128;
    float* Sb = S + (size_t)b * NHW * NHW;
    float4_t acc[4][4];
    ACC_INIT(acc)
    gemm_f16(Q16 + (size_t)b * NHW * NHID + (size_t)m0 * NHID, NHID,
             K16 + (size_t)b * NHW * NHID + (size_t)n0 * NHID, NHID, NHID, As, Bs, acc);
    const int t = threadIdx.x, l = t & 63, quad = l >> 4, l15 = l & 15, w = t >> 6;
    const int wr = (w >> 1) * 64, wc = (w & 1) * 64;
    #pragma unroll
    for (int i = 0; i < 4; ++i)
        #pragma unroll
        for (int j = 0; j < 4; ++j)
            #pragma unroll
            for (int r = 0; r < 4; ++r) {
                int q1 = m0 + wr + i * 16 + quad * 4 + r;
                int q2 = n0 + wc + j * 16 + l15;
                Sb[(size_t)q1 * NHW + q2] = acc[i][j][r];
            }
}

// ---------------- softmax: f32 row in, f16 row out in-place (first 2 KiB of each 4 KiB row) ----------------
__global__ __launch_bounds__(256) void softmax_kernel(float* __restrict__ S) {
    const int t = threadIdx.x, wave = t >> 6, lane = t & 63;
    float* row = S + ((size_t)blockIdx.x * 4 + wave) * NHW;
    float4 v[4];
    float mx = -1e30f;
    #pragma unroll
    for (int j = 0; j < 4; ++j) {
        v[j] = *(const float4*)(row + (lane << 2) + (j << 8));
        mx = fmaxf(mx, fmaxf(fmaxf(v[j].x, v[j].y), fmaxf(v[j].z, v[j].w)));
    }
    #pragma unroll
    for (int off = 32; off >= 1; off >>= 1) mx = fmaxf(mx, __shfl_xor(mx, off, 64));
    float s = 0.f;
    #pragma unroll
    for (int j = 0; j < 4; ++j) {
        v[j].x = __expf(v[j].x - mx); v[j].y = __expf(v[j].y - mx);
        v[j].z = __expf(v[j].z - mx); v[j].w = __expf(v[j].w - mx);
        s += v[j].x + v[j].y + v[j].z + v[j].w;
    }
    #pragma unroll
    for (int off = 32; off >= 1; off >>= 1) s += __shfl_xor(s, off, 64);
    const float inv = 1.0f / s;
    __syncthreads();  // memory barrier: all f32 loads complete before aliasing f16 stores
    _Float16* o = (_Float16*)row;
    #pragma unroll
    for (int j = 0; j < 4; ++j) {
        half4_t h;
        h[0] = (_Float16)(v[j].x * inv); h[1] = (_Float16)(v[j].y * inv);
        h[2] = (_Float16)(v[j].z * inv); h[3] = (_Float16)(v[j].w * inv);
        *(half4_t*)(o + (lane << 2) + (j << 8)) = h;
    }
}

// ---------------- AV: out[b,2048+c,q] = sum_k V16[c][k] A16[q][k] ; K=1024 ----------------
// grid (8, 16, 16). A16 rows live in-place in S (stride 2048 halfs).
__global__ __launch_bounds__(256) void av16_kernel(
    const float* __restrict__ S, float* __restrict__ out) {
    __shared__ __attribute__((aligned(16))) _Float16 As[8192];
    __shared__ __attribute__((aligned(16))) _Float16 Bs[8192];
    const int b = blockIdx.z;
    const _Float16* Vb  = (const _Float16*)((const char*)out + (size_t)b * OUT_BATCH_BYTES);
    const _Float16* A16 = (const _Float16*)(S + (size_t)b * NHW * NHW);
    float* Ob = out + (size_t)b * (2 * NC) * NHW + (size_t)NC * NHW;
    const int m0 = blockIdx.y * 128;  // c
    const int n0 = blockIdx.x * 128;  // q
    float4_t acc[4][4];
    ACC_INIT(acc)
    gemm_f16(Vb + (size_t)m0 * NHW, NHW, A16 + (size_t)n0 * 2048, 2048, NHW, As, Bs, acc);
    const int t = threadIdx.x, l = t & 63, quad = l >> 4, l15 = l & 15, w = t >> 6;
    const int wr = (w >> 1) * 64, wc = (w & 1) * 64;
    #pragma unroll
    for (int i = 0; i < 4; ++i)
        #pragma unroll
        for (int j = 0; j < 4; ++j)
            #pragma unroll
            for (int r = 0; r < 4; ++r) {
                int c = m0 + wr + i * 16 + quad * 4 + r;
                int q = n0 + wc + j * 16 + l15;
                Ob[(size_t)c * NHW + q] = acc[i][j][r];
            }
}

// ---------------- concat first half (runs LAST: out_lo was scratch until now) ----------------
__global__ __launch_bounds__(256) void copy_kernel(const uint4* __restrict__ qf,
                                                   uint4* __restrict__ out) {
    int idx = blockIdx.x * 256 + threadIdx.x;
    int b = idx >> 19;
    int r = idx & 0x7FFFF;
    out[((size_t)b << 20) + r] = qf[idx];
}

extern "C" void kernel_launch(void* const* d_in, const int* in_sizes, int n_in,
                              void* d_out, int out_size, void* d_ws, size_t ws_size,
                              hipStream_t stream) {
    const float* qf   = (const float*)d_in[0];
    const float* pf   = (const float*)d_in[1];
    const float* Wm   = (const float*)d_in[2];
    const float* bias = (const float*)d_in[3];
    float* out = (float*)d_out;

    // ws layout (80 MiB total, same as previous session):
    //   [0,64M):  qf16T [b][hw][c]  -> later aliased by S [b][q1][q2] (f32)
    //   [64,72M): Q16   [b][hw][hid]
    //   [72,80M): K16
    // out scratch (dead before its final writer runs):
    //   per-batch lo 8 MiB: V16 [c][hw] (4 MiB) + pf16T [hw][c] (4 MiB)   (overwritten by copy_kernel)
    //   batch0 hi [8M,9M): W16 [hid][c]                                   (overwritten by av16_kernel)
    _Float16* qT  = (_Float16*)d_ws;
    float*    S   = (float*)d_ws;
    _Float16* Q16 = (_Float16*)((char*)d_ws + ((size_t)64 << 20));
    _Float16* K16 = (_Float16*)((char*)d_ws + ((size_t)72 << 20));
    _Float16* W16 = (_Float16*)((char*)out + ((size_t)8 << 20));

    prep_kernel<<<dim3(16, 32, 32), 256, 0, stream>>>(qf, pf, qT, out);
    wcvt_kernel<<<256, 256, 0, stream>>>(Wm, W16);
    proj16_kernel<<<dim3(2, 8, 32), 256, 0, stream>>>(qT, out, W16, bias, Q16, K16);
    scores16_kernel<<<dim3(8, 8, 16), 256, 0, stream>>>(Q16, K16, S);
    softmax_kernel<<<NB * 256, 256, 0, stream>>>(S);
    av16_kernel<<<dim3(8, 16, 16), 256, 0, stream>>>(S, out);
    copy_kernel<<<32768, 256, 0, stream>>>((const uint4*)qf, (uint4*)out);
}

// Round 5
// 652.283 us; speedup vs baseline: 1.0852x; 1.0618x over previous
//
#include <hip/hip_runtime.h>

// B=16, C=2048, HID=256, HW=1024. fp32 I/O.
// Pipeline: wcvt (W->f16) ; prep_v (pf->V16 streaming) ;
//           proj (f16 MFMA, A staged from f32 X with in-register transpose, reads X ONCE,
//                 proj-Q also writes qf channels [1024,2048) passthrough bit-exact) ;
//           scores (f16 GEMM, XCD-swizzled) ; softmax (f32 in, f16 A in-place) ;
//           av (f16 GEMM, XCD-swizzled) ; copy2 (qf channels [0,1024) -> out, post-av).
#define NB   16
#define NC   2048
#define NHID 256
#define NHW  1024

using half4_t  = __attribute__((ext_vector_type(4))) _Float16;
using half8_t  = __attribute__((ext_vector_type(8))) _Float16;
using float4_t = __attribute__((ext_vector_type(4))) float;

#define OUT_BATCH_BYTES ((size_t)(4096u * 1024u) * 4u)   /* 16 MiB per batch in out */

// ---------------- async 16B global -> LDS ----------------
__device__ __forceinline__ void async_load16(const void* g, void* l) {
    __builtin_amdgcn_global_load_lds((__attribute__((address_space(1))) void*)g,
                                     (__attribute__((address_space(3))) void*)l, 16, 0, 0);
}

// Stage a [nrows x 64-half] tile (128 B rows): LDS linear dest, source pre-swizzled so
// LDS slot sw of row holds logical slot sw^(row&7).  256 threads.
template <int NROWS>
__device__ __forceinline__ void stage_async(const _Float16* __restrict__ src, size_t stride_h,
                                            _Float16* __restrict__ lds, int t) {
    #pragma unroll
    for (int i = 0; i < NROWS / 32; ++i) {
        const int o   = i * 4096 + t * 16;          // byte offset in tile
        const int row = o >> 7;                     // 128 B per row
        const int s   = ((o >> 4) & 7) ^ (row & 7); // logical slot for this LDS slot
        const _Float16* g = src + (size_t)row * stride_h + s * 8;
        async_load16(g, (char*)lds + o);
    }
}

// Fragment read with the same involution.
__device__ __forceinline__ half8_t frag_read(const _Float16* __restrict__ lds, int row, int kk, int quad) {
    const int s = (kk * 4 + quad) ^ (row & 7);
    return *(const half8_t*)((const char*)lds + row * 128 + s * 16);
}

#define ACC_INIT(acc) \
    _Pragma("unroll") for (int i_ = 0; i_ < 4; ++i_) \
    _Pragma("unroll") for (int j_ = 0; j_ < 4; ++j_) \
    _Pragma("unroll") for (int r_ = 0; r_ < 4; ++r_) acc[i_][j_][r_] = 0.f;

// D[128][128] += A[128][K] * B[128][K]^T over K, 4 waves each 64x64. (scores / av)
__device__ __forceinline__ void gemm_f16(const _Float16* __restrict__ A, size_t lda,
                                         const _Float16* __restrict__ B, size_t ldb,
                                         int K, _Float16* __restrict__ As, _Float16* __restrict__ Bs,
                                         float4_t acc[4][4]) {
    const int t = threadIdx.x;
    const int l = t & 63, quad = l >> 4, l15 = l & 15;
    const int w = t >> 6;
    const int wr = (w >> 1) * 64, wc = (w & 1) * 64;
    for (int k0 = 0; k0 < K; k0 += 64) {
        stage_async<128>(A + k0, lda, As, t);
        stage_async<128>(B + k0, ldb, Bs, t);
        __syncthreads();
        #pragma unroll
        for (int kk = 0; kk < 2; ++kk) {
            half8_t af[4], bf[4];
            #pragma unroll
            for (int i = 0; i < 4; ++i) af[i] = frag_read(As, wr + i * 16 + l15, kk, quad);
            #pragma unroll
            for (int j = 0; j < 4; ++j) bf[j] = frag_read(Bs, wc + j * 16 + l15, kk, quad);
            #pragma unroll
            for (int i = 0; i < 4; ++i)
                #pragma unroll
                for (int j = 0; j < 4; ++j)
                    acc[i][j] = __builtin_amdgcn_mfma_f32_16x16x32_f16(af[i], bf[j], acc[i][j], 0, 0, 0);
        }
        __syncthreads();
    }
}

// ---------------- prep_v: pf f32 -> V16 f16 [c][hw], out-lo[0..4M) per batch ----------------
__global__ __launch_bounds__(256) void prep_v_kernel(const float* __restrict__ pf,
                                                     float* __restrict__ out) {
    const int idx = blockIdx.x * 256 + threadIdx.x;   // [0, 16*2^18)
    const int b = idx >> 18;
    const int r = idx & 0x3FFFF;
    const float* src = pf + ((size_t)b << 21) + (size_t)r * 8;
    float4 a = *(const float4*)src;
    float4 c = *(const float4*)(src + 4);
    half8_t h;
    h[0] = (_Float16)a.x; h[1] = (_Float16)a.y; h[2] = (_Float16)a.z; h[3] = (_Float16)a.w;
    h[4] = (_Float16)c.x; h[5] = (_Float16)c.y; h[6] = (_Float16)c.z; h[7] = (_Float16)c.w;
    _Float16* dst = (_Float16*)((char*)out + (size_t)b * OUT_BATCH_BYTES) + (size_t)r * 8;
    *(half8_t*)dst = h;
}

// ---------------- W f32[256][2048] -> f16 ----------------
__global__ __launch_bounds__(256) void wcvt_kernel(const float* __restrict__ W, _Float16* __restrict__ W16) {
    const int idx = (blockIdx.x * 256 + threadIdx.x) * 8;
    float4 a = *(const float4*)(W + idx);
    float4 c = *(const float4*)(W + idx + 4);
    half8_t h;
    h[0] = (_Float16)a.x; h[1] = (_Float16)a.y; h[2] = (_Float16)a.z; h[3] = (_Float16)a.w;
    h[4] = (_Float16)c.x; h[5] = (_Float16)c.y; h[6] = (_Float16)c.z; h[7] = (_Float16)c.w;
    *(half8_t*)(W16 + idx) = h;
}

// ---------------- proj: Q^T/K^T[hw][hid=256] = X^T W^T + b ; K=C=2048, BM=64, BN=256 ----------------
// A staged from f32 X[c][hw] with in-register transpose; B = W16 async-swizzled.
// grid (16 hw-tiles, 1, 32 = which*16+b), 256 threads (4 waves, each 64hw x 64hid).
// proj-Q also streams qf channels [1024,2048) to out-lo[4M..8M) (bit-exact f32 passthrough).
__global__ __launch_bounds__(256) void proj16_kernel(
    const float* __restrict__ qf, const float* __restrict__ pf,
    const _Float16* __restrict__ W16, const float* __restrict__ bias,
    _Float16* __restrict__ Q16, _Float16* __restrict__ K16,
    float* __restrict__ out) {
    __shared__ __attribute__((aligned(16))) _Float16 As[64 * 72];   // padded rows: 72 halfs
    __shared__ __attribute__((aligned(16))) _Float16 Bs[256 * 64];  // swizzled, 32 KiB
    const int z = blockIdx.z, which = z >> 4, b = z & 15;
    const float* X = (which ? pf : qf) + (size_t)b * NC * NHW;
    float* passq = (float*)((char*)out + (size_t)b * OUT_BATCH_BYTES);  // out-lo base (ch0 @ 0)
    _Float16* O = (which ? K16 : Q16) + (size_t)b * NHW * NHID;
    const int m0 = blockIdx.x * 64;   // hw
    const int t = threadIdx.x;
    const int l = t & 63, quad = l >> 4, l15 = l & 15;
    const int w = t >> 6;
    const int wc = w * 64;            // hid
    const int j = t & 15;             // m-group for A staging
    const int g = t >> 4;             // k-group for A staging

    float4_t acc[4][4];
    ACC_INIT(acc)

    for (int k0 = 0; k0 < NC; k0 += 64) {
        // --- stage A: 64(hw) x 64(c) f16, transposed from f32 X[c][hw] ---
        float4 xr[4];
        #pragma unroll
        for (int r = 0; r < 4; ++r)
            xr[r] = *(const float4*)(X + (size_t)(k0 + g * 4 + r) * NHW + m0 + j * 4);
        if (which == 0 && k0 >= 1024) {   // bit-exact qf passthrough, channels [1024,2048)
            #pragma unroll
            for (int r = 0; r < 4; ++r)
                *(float4*)(passq + (size_t)(k0 + g * 4 + r) * NHW + m0 + j * 4) = xr[r];
        }
        #pragma unroll
        for (int e = 0; e < 4; ++e) {
            half4_t h;
            h[0] = (_Float16)((&xr[0].x)[e]);
            h[1] = (_Float16)((&xr[1].x)[e]);
            h[2] = (_Float16)((&xr[2].x)[e]);
            h[3] = (_Float16)((&xr[3].x)[e]);
            *(half4_t*)(As + (j * 4 + e) * 72 + g * 4) = h;
        }
        // --- stage B: W16[256][2048] tile, async swizzled ---
        stage_async<256>(W16 + k0, NC, Bs, t);
        __syncthreads();
        #pragma unroll
        for (int kk = 0; kk < 2; ++kk) {
            half8_t af[4], bf[4];
            #pragma unroll
            for (int i = 0; i < 4; ++i)
                af[i] = *(const half8_t*)(As + (i * 16 + l15) * 72 + kk * 32 + quad * 8);
            #pragma unroll
            for (int jj = 0; jj < 4; ++jj)
                bf[jj] = frag_read(Bs, wc + jj * 16 + l15, kk, quad);
            #pragma unroll
            for (int i = 0; i < 4; ++i)
                #pragma unroll
                for (int jj = 0; jj < 4; ++jj)
                    acc[i][jj] = __builtin_amdgcn_mfma_f32_16x16x32_f16(af[i], bf[jj], acc[i][jj], 0, 0, 0);
        }
        __syncthreads();
    }
    #pragma unroll
    for (int jj = 0; jj < 4; ++jj) {
        const float bv = bias[wc + jj * 16 + l15];
        #pragma unroll
        for (int i = 0; i < 4; ++i)
            #pragma unroll
            for (int r = 0; r < 4; ++r) {
                int hw  = m0 + i * 16 + quad * 4 + r;
                int hid = wc + jj * 16 + l15;
                O[(size_t)hw * NHID + hid] = (_Float16)(acc[i][jj][r] + bv);
            }
    }
}

// ---------------- scores: S[q1][q2] = Q^T . K^T ; K=256 ; XCD-swizzled grid (8,8,16) ----------------
__global__ __launch_bounds__(256) void scores16_kernel(
    const _Float16* __restrict__ Q16, const _Float16* __restrict__ K16, float* __restrict__ S) {
    __shared__ __attribute__((aligned(16))) _Float16 As[8192];
    __shared__ __attribute__((aligned(16))) _Float16 Bs[8192];
    const int oid = blockIdx.x + blockIdx.y * 8 + blockIdx.z * 64;  // [0,1024)
    const int xcd = oid & 7, half = (oid >> 9) & 1, r = (oid >> 3) & 63;
    const int b = xcd * 2 + half;
    const int m0 = (r >> 3) * 128, n0 = (r & 7) * 128;
    float* Sb = S + (size_t)b * NHW * NHW;
    float4_t acc[4][4];
    ACC_INIT(acc)
    gemm_f16(Q16 + (size_t)b * NHW * NHID + (size_t)m0 * NHID, NHID,
             K16 + (size_t)b * NHW * NHID + (size_t)n0 * NHID, NHID, NHID, As, Bs, acc);
    const int t = threadIdx.x, l = t & 63, quad = l >> 4, l15 = l & 15, w = t >> 6;
    const int wr = (w >> 1) * 64, wc = (w & 1) * 64;
    #pragma unroll
    for (int i = 0; i < 4; ++i)
        #pragma unroll
        for (int j = 0; j < 4; ++j)
            #pragma unroll
            for (int rr = 0; rr < 4; ++rr) {
                int q1 = m0 + wr + i * 16 + quad * 4 + rr;
                int q2 = n0 + wc + j * 16 + l15;
                Sb[(size_t)q1 * NHW + q2] = acc[i][j][rr];
            }
}

// ---------------- softmax: f32 row in, f16 row out in-place ----------------
__global__ __launch_bounds__(256) void softmax_kernel(float* __restrict__ S) {
    const int t = threadIdx.x, wave = t >> 6, lane = t & 63;
    float* row = S + ((size_t)blockIdx.x * 4 + wave) * NHW;
    float4 v[4];
    float mx = -1e30f;
    #pragma unroll
    for (int j = 0; j < 4; ++j) {
        v[j] = *(const float4*)(row + (lane << 2) + (j << 8));
        mx = fmaxf(mx, fmaxf(fmaxf(v[j].x, v[j].y), fmaxf(v[j].z, v[j].w)));
    }
    #pragma unroll
    for (int off = 32; off >= 1; off >>= 1) mx = fmaxf(mx, __shfl_xor(mx, off, 64));
    float s = 0.f;
    #pragma unroll
    for (int j = 0; j < 4; ++j) {
        v[j].x = __expf(v[j].x - mx); v[j].y = __expf(v[j].y - mx);
        v[j].z = __expf(v[j].z - mx); v[j].w = __expf(v[j].w - mx);
        s += v[j].x + v[j].y + v[j].z + v[j].w;
    }
    #pragma unroll
    for (int off = 32; off >= 1; off >>= 1) s += __shfl_xor(s, off, 64);
    const float inv = 1.0f / s;
    __syncthreads();  // all f32 loads complete before aliasing f16 stores
    _Float16* o = (_Float16*)row;
    #pragma unroll
    for (int j = 0; j < 4; ++j) {
        half4_t h;
        h[0] = (_Float16)(v[j].x * inv); h[1] = (_Float16)(v[j].y * inv);
        h[2] = (_Float16)(v[j].z * inv); h[3] = (_Float16)(v[j].w * inv);
        *(half4_t*)(o + (lane << 2) + (j << 8)) = h;
    }
}

// ---------------- AV: out[b,2048+c,q] = sum_k V16[c][k] A16[q][k] ; K=1024 ; XCD-swizzled (8,16,16) ----------------
__global__ __launch_bounds__(256) void av16_kernel(
    const float* __restrict__ S, float* __restrict__ out) {
    __shared__ __attribute__((aligned(16))) _Float16 As[8192];
    __shared__ __attribute__((aligned(16))) _Float16 Bs[8192];
    const int oid = blockIdx.x + blockIdx.y * 8 + blockIdx.z * 128;  // [0,2048)
    const int xcd = oid & 7, half = (oid >> 10) & 1, r = (oid >> 3) & 127;
    const int b = xcd * 2 + half;
    const int m0 = (r >> 3) * 128;   // c
    const int n0 = (r & 7) * 128;    // q
    const _Float16* Vb  = (const _Float16*)((const char*)out + (size_t)b * OUT_BATCH_BYTES);
    const _Float16* A16 = (const _Float16*)(S + (size_t)b * NHW * NHW);
    float* Ob = out + (size_t)b * (2 * NC) * NHW + (size_t)NC * NHW;
    float4_t acc[4][4];
    ACC_INIT(acc)
    gemm_f16(Vb + (size_t)m0 * NHW, NHW, A16 + (size_t)n0 * 2048, 2048, NHW, As, Bs, acc);
    const int t = threadIdx.x, l = t & 63, quad = l >> 4, l15 = l & 15, w = t >> 6;
    const int wr = (w >> 1) * 64, wc = (w & 1) * 64;
    #pragma unroll
    for (int i = 0; i < 4; ++i)
        #pragma unroll
        for (int j = 0; j < 4; ++j)
            #pragma unroll
            for (int rr = 0; rr < 4; ++rr) {
                int c = m0 + wr + i * 16 + quad * 4 + rr;
                int q = n0 + wc + j * 16 + l15;
                Ob[(size_t)c * NHW + q] = acc[i][j][rr];
            }
}

// ---------------- copy2: qf channels [0,1024) -> out (post-av16; region was V16 scratch) ----------------
__global__ __launch_bounds__(256) void copy2_kernel(const uint4* __restrict__ qf,
                                                    uint4* __restrict__ out) {
    const int idx = blockIdx.x * 256 + threadIdx.x;   // [0, 16*2^18)
    const int b = idx >> 18;
    const int r = idx & 0x3FFFF;
    out[((size_t)b << 20) + r] = qf[((size_t)b << 19) + r];
}

extern "C" void kernel_launch(void* const* d_in, const int* in_sizes, int n_in,
                              void* d_out, int out_size, void* d_ws, size_t ws_size,
                              hipStream_t stream) {
    const float* qf   = (const float*)d_in[0];
    const float* pf   = (const float*)d_in[1];
    const float* Wm   = (const float*)d_in[2];
    const float* bias = (const float*)d_in[3];
    float* out = (float*)d_out;

    // ws layout (80 MiB):
    //   [0,64M):  S [b][q1][q2] f32 (softmax rewrites rows as f16 A, stride 2048 halfs)
    //   [64,72M): Q16 [b][hw][hid]
    //   [72,80M): K16
    // out scratch (dead before its final writer):
    //   per-batch lo [0,4M):  V16 [c][hw] f16            (overwritten by copy2 post-av16)
    //   per-batch lo [4M,8M): qf ch[1024,2048) passthrough (FINAL data, written by proj)
    //   batch0 hi [8M,9M):    W16 [hid][c]               (overwritten by av16)
    float*    S   = (float*)d_ws;
    _Float16* Q16 = (_Float16*)((char*)d_ws + ((size_t)64 << 20));
    _Float16* K16 = (_Float16*)((char*)d_ws + ((size_t)72 << 20));
    _Float16* W16 = (_Float16*)((char*)out + ((size_t)8 << 20));

    wcvt_kernel<<<256, 256, 0, stream>>>(Wm, W16);
    prep_v_kernel<<<16384, 256, 0, stream>>>(pf, out);
    proj16_kernel<<<dim3(16, 1, 32), 256, 0, stream>>>(qf, pf, W16, bias, Q16, K16, out);
    scores16_kernel<<<dim3(8, 8, 16), 256, 0, stream>>>(Q16, K16, S);
    softmax_kernel<<<NB * 256, 256, 0, stream>>>(S);
    av16_kernel<<<dim3(8, 16, 16), 256, 0, stream>>>(S, out);
    copy2_kernel<<<16384, 256, 0, stream>>>((const uint4*)qf, (uint4*)out);
}

// Round 7
// 612.502 us; speedup vs baseline: 1.1556x; 1.0649x over previous
//
#include <hip/hip_runtime.h>

// B=16, C=2048, HID=256, HW=1024. fp32 I/O.
// Pipeline: wcvt (W->f16) ;
//           proj (f16 MFMA, 512 thr / 8 waves, A staged from f32 X in-register-transposed,
//                 reads X ONCE; proj-Q writes qf ch[1024,2048) passthrough bit-exact;
//                 proj-K writes V16 f16 [c][hw] (prep_v fused)) ;
//           scores (f16 GEMM, XCD-swizzled) ; softmax (f32 in, f16 A in-place) ;
//           av (f16 GEMM, XCD-swizzled) ; copy2 (qf ch[0,1024) -> out, post-av).
#define NB   16
#define NC   2048
#define NHID 256
#define NHW  1024

using half2_t  = __attribute__((ext_vector_type(2))) _Float16;
using half4_t  = __attribute__((ext_vector_type(4))) _Float16;
using half8_t  = __attribute__((ext_vector_type(8))) _Float16;
using float4_t = __attribute__((ext_vector_type(4))) float;

#define OUT_BATCH_BYTES ((size_t)(4096u * 1024u) * 4u)   /* 16 MiB per batch in out */

// ---------------- async 16B global -> LDS ----------------
__device__ __forceinline__ void async_load16(const void* g, void* l) {
    __builtin_amdgcn_global_load_lds((__attribute__((address_space(1))) void*)g,
                                     (__attribute__((address_space(3))) void*)l, 16, 0, 0);
}

// Stage a [nrows x 64-half] tile (128 B rows), 256 threads: LDS linear dest, source
// pre-swizzled so LDS slot sw of row holds logical slot sw^(row&7).
template <int NROWS>
__device__ __forceinline__ void stage_async(const _Float16* __restrict__ src, size_t stride_h,
                                            _Float16* __restrict__ lds, int t) {
    #pragma unroll
    for (int i = 0; i < NROWS / 32; ++i) {
        const int o   = i * 4096 + t * 16;          // byte offset in tile
        const int row = o >> 7;                     // 128 B per row
        const int s   = ((o >> 4) & 7) ^ (row & 7); // logical slot for this LDS slot
        const _Float16* g = src + (size_t)row * stride_h + s * 8;
        async_load16(g, (char*)lds + o);
    }
}

// Same, 512 threads, 256 rows (proj B-tile).
__device__ __forceinline__ void stage_async512(const _Float16* __restrict__ src, size_t stride_h,
                                               _Float16* __restrict__ lds, int t) {
    #pragma unroll
    for (int i = 0; i < 4; ++i) {
        const int o   = i * 8192 + t * 16;
        const int row = o >> 7;
        const int s   = ((o >> 4) & 7) ^ (row & 7);
        const _Float16* g = src + (size_t)row * stride_h + s * 8;
        async_load16(g, (char*)lds + o);
    }
}

// Fragment read with the same involution.
__device__ __forceinline__ half8_t frag_read(const _Float16* __restrict__ lds, int row, int kk, int quad) {
    const int s = (kk * 4 + quad) ^ (row & 7);
    return *(const half8_t*)((const char*)lds + row * 128 + s * 16);
}

#define ACC_INIT(acc) \
    _Pragma("unroll") for (int i_ = 0; i_ < 4; ++i_) \
    _Pragma("unroll") for (int j_ = 0; j_ < 4; ++j_) \
    _Pragma("unroll") for (int r_ = 0; r_ < 4; ++r_) acc[i_][j_][r_] = 0.f;

// D[128][128] += A[128][K] * B[128][K]^T over K, 4 waves each 64x64. (scores / av)
__device__ __forceinline__ void gemm_f16(const _Float16* __restrict__ A, size_t lda,
                                         const _Float16* __restrict__ B, size_t ldb,
                                         int K, _Float16* __restrict__ As, _Float16* __restrict__ Bs,
                                         float4_t acc[4][4]) {
    const int t = threadIdx.x;
    const int l = t & 63, quad = l >> 4, l15 = l & 15;
    const int w = t >> 6;
    const int wr = (w >> 1) * 64, wc = (w & 1) * 64;
    for (int k0 = 0; k0 < K; k0 += 64) {
        stage_async<128>(A + k0, lda, As, t);
        stage_async<128>(B + k0, ldb, Bs, t);
        __syncthreads();
        #pragma unroll
        for (int kk = 0; kk < 2; ++kk) {
            half8_t af[4], bf[4];
            #pragma unroll
            for (int i = 0; i < 4; ++i) af[i] = frag_read(As, wr + i * 16 + l15, kk, quad);
            #pragma unroll
            for (int j = 0; j < 4; ++j) bf[j] = frag_read(Bs, wc + j * 16 + l15, kk, quad);
            #pragma unroll
            for (int i = 0; i < 4; ++i)
                #pragma unroll
                for (int j = 0; j < 4; ++j)
                    acc[i][j] = __builtin_amdgcn_mfma_f32_16x16x32_f16(af[i], bf[j], acc[i][j], 0, 0, 0);
        }
        __syncthreads();
    }
}

// ---------------- W f32[256][2048] -> f16 ----------------
__global__ __launch_bounds__(256) void wcvt_kernel(const float* __restrict__ W, _Float16* __restrict__ W16) {
    const int idx = (blockIdx.x * 256 + threadIdx.x) * 8;
    float4 a = *(const float4*)(W + idx);
    float4 c = *(const float4*)(W + idx + 4);
    half8_t h;
    h[0] = (_Float16)a.x; h[1] = (_Float16)a.y; h[2] = (_Float16)a.z; h[3] = (_Float16)a.w;
    h[4] = (_Float16)c.x; h[5] = (_Float16)c.y; h[6] = (_Float16)c.z; h[7] = (_Float16)c.w;
    *(half8_t*)(W16 + idx) = h;
}

// ---------------- proj: Q^T/K^T[hw][hid=256] = X^T W^T + b ; K=C=2048, BM=64, BN=256 ----------------
// 512 threads, 8 waves (2 hw x 4 hid of 32x64 subtiles). grid (16 hw-tiles, 1, 32 = which*16+b).
// A staged from f32 X[c][hw] with in-register transpose (X read exactly once).
// which==0: also writes qf ch[1024,2048) passthrough (bit-exact f32) to out-lo[4M,8M).
// which==1: also writes V16 f16 [c][hw] to out-lo[0,4M)   (prep_v fused).
__global__ __launch_bounds__(512, 4) void proj16_kernel(
    const float* __restrict__ qf, const float* __restrict__ pf,
    const _Float16* __restrict__ W16, const float* __restrict__ bias,
    _Float16* __restrict__ Q16, _Float16* __restrict__ K16,
    float* __restrict__ out) {
    __shared__ __attribute__((aligned(16))) _Float16 As[64 * 72];   // [hw][c], padded rows
    __shared__ __attribute__((aligned(16))) _Float16 Bs[256 * 64];  // swizzled, 32 KiB
    const int z = blockIdx.z, which = z >> 4, b = z & 15;
    const float* X = (which ? pf : qf) + (size_t)b * NC * NHW;
    float*     passq = (float*)((char*)out + (size_t)b * OUT_BATCH_BYTES);
    _Float16*  V16   = (_Float16*)((char*)out + (size_t)b * OUT_BATCH_BYTES);
    _Float16* O = (which ? K16 : Q16) + (size_t)b * NHW * NHID;
    const int m0 = blockIdx.x * 64;   // hw
    const int t = threadIdx.x;
    const int l = t & 63, quad = l >> 4, l15 = l & 15;
    const int w = t >> 6;
    const int wr = (w >> 2) * 32;     // hw subtile {0,32}
    const int wc = (w & 3) * 64;      // hid subtile {0,64,128,192}
    const int j  = t & 15;            // hw-group (4 hw) for staging
    const int gs = t >> 4;            // c-pair group [0,32) for staging

    float4_t acc[2][4];
    #pragma unroll
    for (int i = 0; i < 2; ++i)
        #pragma unroll
        for (int jj = 0; jj < 4; ++jj)
            #pragma unroll
            for (int r = 0; r < 4; ++r) acc[i][jj][r] = 0.f;

    for (int k0 = 0; k0 < NC; k0 += 64) {
        const int c0 = k0 + gs * 2;
        // --- load 2 c-rows x 4 hw (f32), the block's only X read ---
        float4 x0 = *(const float4*)(X + (size_t)c0 * NHW + m0 + j * 4);
        float4 x1 = *(const float4*)(X + (size_t)(c0 + 1) * NHW + m0 + j * 4);
        half4_t hv0, hv1;
        #pragma unroll
        for (int e = 0; e < 4; ++e) { hv0[e] = (_Float16)((&x0.x)[e]); hv1[e] = (_Float16)((&x1.x)[e]); }
        if (which) {                 // fused prep_v: V16[c][hw]
            *(half4_t*)(V16 + (size_t)c0 * NHW + m0 + j * 4)       = hv0;
            *(half4_t*)(V16 + (size_t)(c0 + 1) * NHW + m0 + j * 4) = hv1;
        } else if (k0 >= 1024) {     // bit-exact qf passthrough, ch [1024,2048)
            *(float4*)(passq + (size_t)c0 * NHW + m0 + j * 4)       = x0;
            *(float4*)(passq + (size_t)(c0 + 1) * NHW + m0 + j * 4) = x1;
        }
        // --- transpose-store to As[hw][c] ---
        #pragma unroll
        for (int e = 0; e < 4; ++e) {
            half2_t h2; h2[0] = hv0[e]; h2[1] = hv1[e];
            *(half2_t*)(As + (j * 4 + e) * 72 + gs * 2) = h2;
        }
        // --- stage B: W16[256][2048] tile, async swizzled ---
        stage_async512(W16 + k0, NC, Bs, t);
        __syncthreads();
        #pragma unroll
        for (int kk = 0; kk < 2; ++kk) {
            half8_t af[2], bf[4];
            #pragma unroll
            for (int i = 0; i < 2; ++i)
                af[i] = *(const half8_t*)(As + (wr + i * 16 + l15) * 72 + kk * 32 + quad * 8);
            #pragma unroll
            for (int jj = 0; jj < 4; ++jj)
                bf[jj] = frag_read(Bs, wc + jj * 16 + l15, kk, quad);
            #pragma unroll
            for (int i = 0; i < 2; ++i)
                #pragma unroll
                for (int jj = 0; jj < 4; ++jj)
                    acc[i][jj] = __builtin_amdgcn_mfma_f32_16x16x32_f16(af[i], bf[jj], acc[i][jj], 0, 0, 0);
        }
        __syncthreads();
    }
    #pragma unroll
    for (int jj = 0; jj < 4; ++jj) {
        const float bv = bias[wc + jj * 16 + l15];
        #pragma unroll
        for (int i = 0; i < 2; ++i)
            #pragma unroll
            for (int r = 0; r < 4; ++r) {
                int hw  = m0 + wr + i * 16 + quad * 4 + r;
                int hid = wc + jj * 16 + l15;
                O[(size_t)hw * NHID + hid] = (_Float16)(acc[i][jj][r] + bv);
            }
    }
}

// ---------------- scores: S[q1][q2] = Q^T . K^T ; K=256 ; XCD-swizzled grid (8,8,16) ----------------
__global__ __launch_bounds__(256) void scores16_kernel(
    const _Float16* __restrict__ Q16, const _Float16* __restrict__ K16, float* __restrict__ S) {
    __shared__ __attribute__((aligned(16))) _Float16 As[8192];
    __shared__ __attribute__((aligned(16))) _Float16 Bs[8192];
    const int oid = blockIdx.x + blockIdx.y * 8 + blockIdx.z * 64;  // [0,1024)
    const int xcd = oid & 7, half = (oid >> 9) & 1, r = (oid >> 3) & 63;
    const int b = xcd * 2 + half;
    const int m0 = (r >> 3) * 128, n0 = (r & 7) * 128;
    float* Sb = S + (size_t)b * NHW * NHW;
    float4_t acc[4][4];
    ACC_INIT(acc)
    gemm_f16(Q16 + (size_t)b * NHW * NHID + (size_t)m0 * NHID, NHID,
             K16 + (size_t)b * NHW * NHID + (size_t)n0 * NHID, NHID, NHID, As, Bs, acc);
    const int t = threadIdx.x, l = t & 63, quad = l >> 4, l15 = l & 15, w = t >> 6;
    const int wr = (w >> 1) * 64, wc = (w & 1) * 64;
    #pragma unroll
    for (int i = 0; i < 4; ++i)
        #pragma unroll
        for (int j = 0; j < 4; ++j)
            #pragma unroll
            for (int rr = 0; rr < 4; ++rr) {
                int q1 = m0 + wr + i * 16 + quad * 4 + rr;
                int q2 = n0 + wc + j * 16 + l15;
                Sb[(size_t)q1 * NHW + q2] = acc[i][j][rr];
            }
}

// ---------------- softmax: f32 row in, f16 row out in-place ----------------
__global__ __launch_bounds__(256) void softmax_kernel(float* __restrict__ S) {
    const int t = threadIdx.x, wave = t >> 6, lane = t & 63;
    float* row = S + ((size_t)blockIdx.x * 4 + wave) * NHW;
    float4 v[4];
    float mx = -1e30f;
    #pragma unroll
    for (int j = 0; j < 4; ++j) {
        v[j] = *(const float4*)(row + (lane << 2) + (j << 8));
        mx = fmaxf(mx, fmaxf(fmaxf(v[j].x, v[j].y), fmaxf(v[j].z, v[j].w)));
    }
    #pragma unroll
    for (int off = 32; off >= 1; off >>= 1) mx = fmaxf(mx, __shfl_xor(mx, off, 64));
    float s = 0.f;
    #pragma unroll
    for (int j = 0; j < 4; ++j) {
        v[j].x = __expf(v[j].x - mx); v[j].y = __expf(v[j].y - mx);
        v[j].z = __expf(v[j].z - mx); v[j].w = __expf(v[j].w - mx);
        s += v[j].x + v[j].y + v[j].z + v[j].w;
    }
    #pragma unroll
    for (int off = 32; off >= 1; off >>= 1) s += __shfl_xor(s, off, 64);
    const float inv = 1.0f / s;
    __syncthreads();  // all f32 loads complete before aliasing f16 stores
    _Float16* o = (_Float16*)row;
    #pragma unroll
    for (int j = 0; j < 4; ++j) {
        half4_t h;
        h[0] = (_Float16)(v[j].x * inv); h[1] = (_Float16)(v[j].y * inv);
        h[2] = (_Float16)(v[j].z * inv); h[3] = (_Float16)(v[j].w * inv);
        *(half4_t*)(o + (lane << 2) + (j << 8)) = h;
    }
}

// ---------------- AV: out[b,2048+c,q] = sum_k V16[c][k] A16[q][k] ; K=1024 ; XCD-swizzled (8,16,16) ----------------
__global__ __launch_bounds__(256) void av16_kernel(
    const float* __restrict__ S, float* __restrict__ out) {
    __shared__ __attribute__((aligned(16))) _Float16 As[8192];
    __shared__ __attribute__((aligned(16))) _Float16 Bs[8192];
    const int oid = blockIdx.x + blockIdx.y * 8 + blockIdx.z * 128;  // [0,2048)
    const int xcd = oid & 7, half = (oid >> 10) & 1, r = (oid >> 3) & 127;
    const int b = xcd * 2 + half;
    const int m0 = (r >> 3) * 128;   // c
    const int n0 = (r & 7) * 128;    // q
    const _Float16* Vb  = (const _Float16*)((const char*)out + (size_t)b * OUT_BATCH_BYTES);
    const _Float16* A16 = (const _Float16*)(S + (size_t)b * NHW * NHW);
    float* Ob = out + (size_t)b * (2 * NC) * NHW + (size_t)NC * NHW;
    float4_t acc[4][4];
    ACC_INIT(acc)
    gemm_f16(Vb + (size_t)m0 * NHW, NHW, A16 + (size_t)n0 * 2048, 2048, NHW, As, Bs, acc);
    const int t = threadIdx.x, l = t & 63, quad = l >> 4, l15 = l & 15, w = t >> 6;
    const int wr = (w >> 1) * 64, wc = (w & 1) * 64;
    #pragma unroll
    for (int i = 0; i < 4; ++i)
        #pragma unroll
        for (int j = 0; j < 4; ++j)
            #pragma unroll
            for (int rr = 0; rr < 4; ++rr) {
                int c = m0 + wr + i * 16 + quad * 4 + rr;
                int q = n0 + wc + j * 16 + l15;
                Ob[(size_t)c * NHW + q] = acc[i][j][rr];
            }
}

// ---------------- copy2: qf channels [0,1024) -> out (post-av16; region was V16 scratch) ----------------
__global__ __launch_bounds__(256) void copy2_kernel(const uint4* __restrict__ qf,
                                                    uint4* __restrict__ out) {
    const int idx = blockIdx.x * 256 + threadIdx.x;   // [0, 16*2^18)
    const int b = idx >> 18;
    const int r = idx & 0x3FFFF;
    out[((size_t)b << 20) + r] = qf[((size_t)b << 19) + r];
}

extern "C" void kernel_launch(void* const* d_in, const int* in_sizes, int n_in,
                              void* d_out, int out_size, void* d_ws, size_t ws_size,
                              hipStream_t stream) {
    const float* qf   = (const float*)d_in[0];
    const float* pf   = (const float*)d_in[1];
    const float* Wm   = (const float*)d_in[2];
    const float* bias = (const float*)d_in[3];
    float* out = (float*)d_out;

    // ws layout (80 MiB):
    //   [0,64M):  S [b][q1][q2] f32 (softmax rewrites rows as f16 A, stride 2048 halfs)
    //   [64,72M): Q16 [b][hw][hid]
    //   [72,80M): K16
    // out scratch (dead before its final writer):
    //   per-batch lo [0,4M):  V16 [c][hw] f16 (written by proj-K; overwritten by copy2 post-av16)
    //   per-batch lo [4M,8M): qf ch[1024,2048) passthrough (FINAL data, written by proj-Q)
    //   batch0 hi [8M,9M):    W16 [hid][c]    (read only by proj; overwritten by av16)
    float*    S   = (float*)d_ws;
    _Float16* Q16 = (_Float16*)((char*)d_ws + ((size_t)64 << 20));
    _Float16* K16 = (_Float16*)((char*)d_ws + ((size_t)72 << 20));
    _Float16* W16 = (_Float16*)((char*)out + ((size_t)8 << 20));

    wcvt_kernel<<<256, 256, 0, stream>>>(Wm, W16);
    proj16_kernel<<<dim3(16, 1, 32), 512, 0, stream>>>(qf, pf, W16, bias, Q16, K16, out);
    scores16_kernel<<<dim3(8, 8, 16), 256, 0, stream>>>(Q16, K16, S);
    softmax_kernel<<<NB * 256, 256, 0, stream>>>(S);
    av16_kernel<<<dim3(8, 16, 16), 256, 0, stream>>>(S, out);
    copy2_kernel<<<16384, 256, 0, stream>>>((const uint4*)qf, (uint4*)out);
}

// Round 8
// 590.933 us; speedup vs baseline: 1.1978x; 1.0365x over previous
//
#include <hip/hip_runtime.h>

// B=16, C=2048, HID=256, HW=1024. fp32 I/O.
// Pipeline: wcvt (W->f16) ;
//           proj (f16 MFMA, 512 thr, A reg-staged from f32 X w/ transpose+T14 prefetch,
//                 reads X ONCE; proj-Q writes FULL qf ch[0,2048) passthrough bit-exact) ;
//           scores (f16 GEMM, XCD-swizzled) ; softmax (f32 in, f16 A in-place) ;
//           av (f16 GEMM, V reg-staged from pf f32 w/ T14 prefetch; no V16, no copy2).
#define NB   16
#define NC   2048
#define NHID 256
#define NHW  1024

using half2_t  = __attribute__((ext_vector_type(2))) _Float16;
using half4_t  = __attribute__((ext_vector_type(4))) _Float16;
using half8_t  = __attribute__((ext_vector_type(8))) _Float16;
using float4_t = __attribute__((ext_vector_type(4))) float;

#define OUT_BATCH_BYTES ((size_t)(4096u * 1024u) * 4u)   /* 16 MiB per batch in out */

// ---------------- async 16B global -> LDS ----------------
__device__ __forceinline__ void async_load16(const void* g, void* l) {
    __builtin_amdgcn_global_load_lds((__attribute__((address_space(1))) void*)g,
                                     (__attribute__((address_space(3))) void*)l, 16, 0, 0);
}

// Stage a [nrows x 64-half] tile (128 B rows), 256 threads: LDS linear dest, source
// pre-swizzled so LDS slot sw of row holds logical slot sw^(row&7).
template <int NROWS>
__device__ __forceinline__ void stage_async(const _Float16* __restrict__ src, size_t stride_h,
                                            _Float16* __restrict__ lds, int t) {
    #pragma unroll
    for (int i = 0; i < NROWS / 32; ++i) {
        const int o   = i * 4096 + t * 16;          // byte offset in tile
        const int row = o >> 7;                     // 128 B per row
        const int s   = ((o >> 4) & 7) ^ (row & 7); // logical slot for this LDS slot
        const _Float16* g = src + (size_t)row * stride_h + s * 8;
        async_load16(g, (char*)lds + o);
    }
}

// Same, 512 threads, 256 rows (proj B-tile).
__device__ __forceinline__ void stage_async512(const _Float16* __restrict__ src, size_t stride_h,
                                               _Float16* __restrict__ lds, int t) {
    #pragma unroll
    for (int i = 0; i < 4; ++i) {
        const int o   = i * 8192 + t * 16;
        const int row = o >> 7;
        const int s   = ((o >> 4) & 7) ^ (row & 7);
        const _Float16* g = src + (size_t)row * stride_h + s * 8;
        async_load16(g, (char*)lds + o);
    }
}

// Fragment read with the same involution.
__device__ __forceinline__ half8_t frag_read(const _Float16* __restrict__ lds, int row, int kk, int quad) {
    const int s = (kk * 4 + quad) ^ (row & 7);
    return *(const half8_t*)((const char*)lds + row * 128 + s * 16);
}

#define ACC_INIT(acc) \
    _Pragma("unroll") for (int i_ = 0; i_ < 4; ++i_) \
    _Pragma("unroll") for (int j_ = 0; j_ < 4; ++j_) \
    _Pragma("unroll") for (int r_ = 0; r_ < 4; ++r_) acc[i_][j_][r_] = 0.f;

// D[128][128] += A[128][K] * B[128][K]^T over K, 4 waves each 64x64. (scores only)
__device__ __forceinline__ void gemm_f16(const _Float16* __restrict__ A, size_t lda,
                                         const _Float16* __restrict__ B, size_t ldb,
                                         int K, _Float16* __restrict__ As, _Float16* __restrict__ Bs,
                                         float4_t acc[4][4]) {
    const int t = threadIdx.x;
    const int l = t & 63, quad = l >> 4, l15 = l & 15;
    const int w = t >> 6;
    const int wr = (w >> 1) * 64, wc = (w & 1) * 64;
    for (int k0 = 0; k0 < K; k0 += 64) {
        stage_async<128>(A + k0, lda, As, t);
        stage_async<128>(B + k0, ldb, Bs, t);
        __syncthreads();
        #pragma unroll
        for (int kk = 0; kk < 2; ++kk) {
            half8_t af[4], bf[4];
            #pragma unroll
            for (int i = 0; i < 4; ++i) af[i] = frag_read(As, wr + i * 16 + l15, kk, quad);
            #pragma unroll
            for (int j = 0; j < 4; ++j) bf[j] = frag_read(Bs, wc + j * 16 + l15, kk, quad);
            #pragma unroll
            for (int i = 0; i < 4; ++i)
                #pragma unroll
                for (int j = 0; j < 4; ++j)
                    acc[i][j] = __builtin_amdgcn_mfma_f32_16x16x32_f16(af[i], bf[j], acc[i][j], 0, 0, 0);
        }
        __syncthreads();
    }
}

// ---------------- W f32[256][2048] -> f16 ----------------
__global__ __launch_bounds__(256) void wcvt_kernel(const float* __restrict__ W, _Float16* __restrict__ W16) {
    const int idx = (blockIdx.x * 256 + threadIdx.x) * 8;
    float4 a = *(const float4*)(W + idx);
    float4 c = *(const float4*)(W + idx + 4);
    half8_t h;
    h[0] = (_Float16)a.x; h[1] = (_Float16)a.y; h[2] = (_Float16)a.z; h[3] = (_Float16)a.w;
    h[4] = (_Float16)c.x; h[5] = (_Float16)c.y; h[6] = (_Float16)c.z; h[7] = (_Float16)c.w;
    *(half8_t*)(W16 + idx) = h;
}

// ---------------- proj: Q^T/K^T[hw][hid=256] = X^T W^T + b ; K=C=2048, BM=64, BN=256 ----------------
// 512 threads, 8 waves (2 hw x 4 hid of 32x64 subtiles). grid (16 hw-tiles, 1, 32 = which*16+b).
// A reg-staged from f32 X[c][hw] w/ in-register transpose; T14: next step's X loads issued
// before the barrier so their latency drains concurrently with the W16 global_load_lds.
// which==0: writes FULL qf ch[0,2048) passthrough (bit-exact f32) to out-lo[0,8M).
__global__ __launch_bounds__(512, 4) void proj16_kernel(
    const float* __restrict__ qf, const float* __restrict__ pf,
    const _Float16* __restrict__ W16, const float* __restrict__ bias,
    _Float16* __restrict__ Q16, _Float16* __restrict__ K16,
    float* __restrict__ out) {
    __shared__ __attribute__((aligned(16))) _Float16 As[64 * 72];   // [hw][c], padded rows
    __shared__ __attribute__((aligned(16))) _Float16 Bs[256 * 64];  // swizzled, 32 KiB
    const int z = blockIdx.z, which = z >> 4, b = z & 15;
    const float* X = (which ? pf : qf) + (size_t)b * NC * NHW;
    float* passq = (float*)((char*)out + (size_t)b * OUT_BATCH_BYTES);  // ch c at passq + c*NHW
    _Float16* O = (which ? K16 : Q16) + (size_t)b * NHW * NHID;
    const int m0 = blockIdx.x * 64;   // hw
    const int t = threadIdx.x;
    const int l = t & 63, quad = l >> 4, l15 = l & 15;
    const int w = t >> 6;
    const int wr = (w >> 2) * 32;     // hw subtile {0,32}
    const int wc = (w & 3) * 64;      // hid subtile {0,64,128,192}
    const int j  = t & 15;            // hw-group (4 hw) for staging
    const int gs = t >> 4;            // c-pair group [0,32) for staging

    float4_t acc[2][4];
    #pragma unroll
    for (int i = 0; i < 2; ++i)
        #pragma unroll
        for (int jj = 0; jj < 4; ++jj)
            #pragma unroll
            for (int r = 0; r < 4; ++r) acc[i][jj][r] = 0.f;

    // T14 prologue: first K-step's X rows
    const float* X0 = X + (size_t)(gs * 2) * NHW + m0 + j * 4;
    float4 x0 = *(const float4*)X0;
    float4 x1 = *(const float4*)(X0 + NHW);

    for (int k0 = 0; k0 < NC; k0 += 64) {
        // --- stage B: W16 tile, async swizzled (completion drains at the barrier) ---
        stage_async512(W16 + k0, NC, Bs, t);
        // --- passthrough (bit-exact f32, all channels) ---
        if (which == 0) {
            float* pq = passq + (size_t)(k0 + gs * 2) * NHW + m0 + j * 4;
            *(float4*)pq = x0;
            *(float4*)(pq + NHW) = x1;
        }
        // --- transpose-convert current X regs -> As[hw][c] ---
        #pragma unroll
        for (int e = 0; e < 4; ++e) {
            half2_t h2;
            h2[0] = (_Float16)((&x0.x)[e]);
            h2[1] = (_Float16)((&x1.x)[e]);
            *(half2_t*)(As + (j * 4 + e) * 72 + gs * 2) = h2;
        }
        // --- T14: issue next step's X loads; latency hides under the barrier drain ---
        if (k0 + 64 < NC) {
            const float* Xn = X + (size_t)(k0 + 64 + gs * 2) * NHW + m0 + j * 4;
            x0 = *(const float4*)Xn;
            x1 = *(const float4*)(Xn + NHW);
        }
        __syncthreads();
        #pragma unroll
        for (int kk = 0; kk < 2; ++kk) {
            half8_t af[2], bf[4];
            #pragma unroll
            for (int i = 0; i < 2; ++i)
                af[i] = *(const half8_t*)(As + (wr + i * 16 + l15) * 72 + kk * 32 + quad * 8);
            #pragma unroll
            for (int jj = 0; jj < 4; ++jj)
                bf[jj] = frag_read(Bs, wc + jj * 16 + l15, kk, quad);
            #pragma unroll
            for (int i = 0; i < 2; ++i)
                #pragma unroll
                for (int jj = 0; jj < 4; ++jj)
                    acc[i][jj] = __builtin_amdgcn_mfma_f32_16x16x32_f16(af[i], bf[jj], acc[i][jj], 0, 0, 0);
        }
        __syncthreads();
    }
    #pragma unroll
    for (int jj = 0; jj < 4; ++jj) {
        const float bv = bias[wc + jj * 16 + l15];
        #pragma unroll
        for (int i = 0; i < 2; ++i)
            #pragma unroll
            for (int r = 0; r < 4; ++r) {
                int hw  = m0 + wr + i * 16 + quad * 4 + r;
                int hid = wc + jj * 16 + l15;
                O[(size_t)hw * NHID + hid] = (_Float16)(acc[i][jj][r] + bv);
            }
    }
}

// ---------------- scores: S[q1][q2] = Q^T . K^T ; K=256 ; XCD-swizzled grid (8,8,16) ----------------
__global__ __launch_bounds__(256) void scores16_kernel(
    const _Float16* __restrict__ Q16, const _Float16* __restrict__ K16, float* __restrict__ S) {
    __shared__ __attribute__((aligned(16))) _Float16 As[8192];
    __shared__ __attribute__((aligned(16))) _Float16 Bs[8192];
    const int oid = blockIdx.x + blockIdx.y * 8 + blockIdx.z * 64;  // [0,1024)
    const int xcd = oid & 7, half = (oid >> 9) & 1, r = (oid >> 3) & 63;
    const int b = xcd * 2 + half;
    const int m0 = (r >> 3) * 128, n0 = (r & 7) * 128;
    float* Sb = S + (size_t)b * NHW * NHW;
    float4_t acc[4][4];
    ACC_INIT(acc)
    gemm_f16(Q16 + (size_t)b * NHW * NHID + (size_t)m0 * NHID, NHID,
             K16 + (size_t)b * NHW * NHID + (size_t)n0 * NHID, NHID, NHID, As, Bs, acc);
    const int t = threadIdx.x, l = t & 63, quad = l >> 4, l15 = l & 15, w = t >> 6;
    const int wr = (w >> 1) * 64, wc = (w & 1) * 64;
    #pragma unroll
    for (int i = 0; i < 4; ++i)
        #pragma unroll
        for (int j = 0; j < 4; ++j)
            #pragma unroll
            for (int rr = 0; rr < 4; ++rr) {
                int q1 = m0 + wr + i * 16 + quad * 4 + rr;
                int q2 = n0 + wc + j * 16 + l15;
                Sb[(size_t)q1 * NHW + q2] = acc[i][j][rr];
            }
}

// ---------------- softmax: f32 row in, f16 row out in-place ----------------
__global__ __launch_bounds__(256) void softmax_kernel(float* __restrict__ S) {
    const int t = threadIdx.x, wave = t >> 6, lane = t & 63;
    float* row = S + ((size_t)blockIdx.x * 4 + wave) * NHW;
    float4 v[4];
    float mx = -1e30f;
    #pragma unroll
    for (int j = 0; j < 4; ++j) {
        v[j] = *(const float4*)(row + (lane << 2) + (j << 8));
        mx = fmaxf(mx, fmaxf(fmaxf(v[j].x, v[j].y), fmaxf(v[j].z, v[j].w)));
    }
    #pragma unroll
    for (int off = 32; off >= 1; off >>= 1) mx = fmaxf(mx, __shfl_xor(mx, off, 64));
    float s = 0.f;
    #pragma unroll
    for (int j = 0; j < 4; ++j) {
        v[j].x = __expf(v[j].x - mx); v[j].y = __expf(v[j].y - mx);
        v[j].z = __expf(v[j].z - mx); v[j].w = __expf(v[j].w - mx);
        s += v[j].x + v[j].y + v[j].z + v[j].w;
    }
    #pragma unroll
    for (int off = 32; off >= 1; off >>= 1) s += __shfl_xor(s, off, 64);
    const float inv = 1.0f / s;
    __syncthreads();  // all f32 loads complete before aliasing f16 stores
    _Float16* o = (_Float16*)row;
    #pragma unroll
    for (int j = 0; j < 4; ++j) {
        half4_t h;
        h[0] = (_Float16)(v[j].x * inv); h[1] = (_Float16)(v[j].y * inv);
        h[2] = (_Float16)(v[j].z * inv); h[3] = (_Float16)(v[j].w * inv);
        *(half4_t*)(o + (lane << 2) + (j << 8)) = h;
    }
}

// ---------------- AV: out[b,2048+c,q] = sum_k V[c][k] A16[q][k] ; K=1024 ; XCD-swizzled (8,16,16) ----------------
// V reg-staged from pf f32 (convert at ds_write time) with T14 prefetch; B = A16 via global_load_lds.
__global__ __launch_bounds__(256) void av16_kernel(
    const float* __restrict__ pf, const float* __restrict__ S, float* __restrict__ out) {
    __shared__ __attribute__((aligned(16))) _Float16 As[8192];
    __shared__ __attribute__((aligned(16))) _Float16 Bs[8192];
    const int oid = blockIdx.x + blockIdx.y * 8 + blockIdx.z * 128;  // [0,2048)
    const int xcd = oid & 7, half = (oid >> 10) & 1, r = (oid >> 3) & 127;
    const int b = xcd * 2 + half;
    const int m0 = (r >> 3) * 128;   // c
    const int n0 = (r & 7) * 128;    // q
    const float* Vb = pf + (size_t)b * NC * NHW;      // f32 [c][hw]
    const _Float16* A16 = (const _Float16*)(S + (size_t)b * NHW * NHW);
    float* Ob = out + (size_t)b * (2 * NC) * NHW + (size_t)NC * NHW;
    const int t = threadIdx.x, l = t & 63, quad = l >> 4, l15 = l & 15, w = t >> 6;
    const int wr = (w >> 1) * 64, wc = (w & 1) * 64;

    float4_t acc[4][4];
    ACC_INIT(acc)

    // T14 prologue: first K-step's V rows (f32, 32 B per thread-slot, 4 slots)
    float4 vr0[4], vr1[4];
    #pragma unroll
    for (int i = 0; i < 4; ++i) {
        const int flat = i * 256 + t, rr = flat >> 3, ss = flat & 7;
        const float* p = Vb + (size_t)(m0 + rr) * NHW + ss * 8;
        vr0[i] = *(const float4*)p;
        vr1[i] = *(const float4*)(p + 4);
    }

    for (int k0 = 0; k0 < NHW; k0 += 64) {
        stage_async<128>(A16 + (size_t)n0 * 2048 + k0, 2048, Bs, t);   // B operand
        // convert current V regs -> As (swizzled slots, matches frag_read)
        #pragma unroll
        for (int i = 0; i < 4; ++i) {
            const int flat = i * 256 + t, rr = flat >> 3, ss = flat & 7;
            half8_t h;
            #pragma unroll
            for (int e = 0; e < 4; ++e) {
                h[e]     = (_Float16)((&vr0[i].x)[e]);
                h[4 + e] = (_Float16)((&vr1[i].x)[e]);
            }
            *(half8_t*)((char*)As + rr * 128 + ((ss ^ (rr & 7)) * 16)) = h;
        }
        // T14: issue next step's V loads; latency drains with the gload_lds at the barrier
        if (k0 + 64 < NHW) {
            #pragma unroll
            for (int i = 0; i < 4; ++i) {
                const int flat = i * 256 + t, rr = flat >> 3, ss = flat & 7;
                const float* p = Vb + (size_t)(m0 + rr) * NHW + (k0 + 64) + ss * 8;
                vr0[i] = *(const float4*)p;
                vr1[i] = *(const float4*)(p + 4);
            }
        }
        __syncthreads();
        #pragma unroll
        for (int kk = 0; kk < 2; ++kk) {
            half8_t af[4], bf[4];
            #pragma unroll
            for (int i = 0; i < 4; ++i) af[i] = frag_read(As, wr + i * 16 + l15, kk, quad);
            #pragma unroll
            for (int j = 0; j < 4; ++j) bf[j] = frag_read(Bs, wc + j * 16 + l15, kk, quad);
            #pragma unroll
            for (int i = 0; i < 4; ++i)
                #pragma unroll
                for (int j = 0; j < 4; ++j)
                    acc[i][j] = __builtin_amdgcn_mfma_f32_16x16x32_f16(af[i], bf[j], acc[i][j], 0, 0, 0);
        }
        __syncthreads();
    }
    #pragma unroll
    for (int i = 0; i < 4; ++i)
        #pragma unroll
        for (int j = 0; j < 4; ++j)
            #pragma unroll
            for (int rr = 0; rr < 4; ++rr) {
                int c = m0 + wr + i * 16 + quad * 4 + rr;
                int q = n0 + wc + j * 16 + l15;
                Ob[(size_t)c * NHW + q] = acc[i][j][rr];
            }
}

extern "C" void kernel_launch(void* const* d_in, const int* in_sizes, int n_in,
                              void* d_out, int out_size, void* d_ws, size_t ws_size,
                              hipStream_t stream) {
    const float* qf   = (const float*)d_in[0];
    const float* pf   = (const float*)d_in[1];
    const float* Wm   = (const float*)d_in[2];
    const float* bias = (const float*)d_in[3];
    float* out = (float*)d_out;

    // ws layout (80 MiB):
    //   [0,64M):  S [b][q1][q2] f32 (softmax rewrites rows as f16 A, stride 2048 halfs)
    //   [64,72M): Q16 [b][hw][hid]
    //   [72,80M): K16
    // out:
    //   per-batch lo [0,8M):  FULL qf ch[0,2048) passthrough, written by proj-Q (final data)
    //   batch0 hi [8M,9M):    W16 [hid][c] scratch (read only by proj; overwritten by av16)
    //   per-batch hi [8M,16M): aligned output, written by av16
    float*    S   = (float*)d_ws;
    _Float16* Q16 = (_Float16*)((char*)d_ws + ((size_t)64 << 20));
    _Float16* K16 = (_Float16*)((char*)d_ws + ((size_t)72 << 20));
    _Float16* W16 = (_Float16*)((char*)out + ((size_t)8 << 20));

    wcvt_kernel<<<256, 256, 0, stream>>>(Wm, W16);
    proj16_kernel<<<dim3(16, 1, 32), 512, 0, stream>>>(qf, pf, W16, bias, Q16, K16, out);
    scores16_kernel<<<dim3(8, 8, 16), 256, 0, stream>>>(Q16, K16, S);
    softmax_kernel<<<NB * 256, 256, 0, stream>>>(S);
    av16_kernel<<<dim3(8, 16, 16), 256, 0, stream>>>(pf, S, out);
}